// Round 3
// baseline (156.225 us; speedup 1.0000x reference)
//
#include <hip/hip_runtime.h>
#include <hip/hip_bf16.h>

typedef unsigned short u16;
typedef __bf16 bf16;
typedef __attribute__((ext_vector_type(8))) __bf16 bf16x8;
typedef __attribute__((ext_vector_type(4))) __bf16 bf16x4;
typedef __attribute__((ext_vector_type(4))) float f32x4;

#define MFMA16(A,B,C) __builtin_amdgcn_mfma_f32_16x16x32_bf16(A,B,C,0,0,0)

constexpr int NTOK = 49;
constexpr int CH   = 128;
// softmax scale folded into exp2: SCALE * log2(e)
constexpr float CEXP = 0.17677669529663687f * 1.4426950408889634f;

__device__ __forceinline__ bf16x8 lds_v8(const u16* base, int byteoff) {
    return *reinterpret_cast<const bf16x8*>(reinterpret_cast<const char*>(base) + byteoff);
}
// 16B fragment load from 8B-aligned address (stride-72 rows): two b64 reads
__device__ __forceinline__ bf16x8 lds_v8_u8(const u16* base, int byteoff) {
    bf16x4 lo = *reinterpret_cast<const bf16x4*>(reinterpret_cast<const char*>(base) + byteoff);
    bf16x4 hi = *reinterpret_cast<const bf16x4*>(reinterpret_cast<const char*>(base) + byteoff + 8);
    bf16x8 r;
    r[0]=lo[0]; r[1]=lo[1]; r[2]=lo[2]; r[3]=lo[3];
    r[4]=hi[0]; r[5]=hi[1]; r[6]=hi[2]; r[7]=hi[3];
    return r;
}
__device__ __forceinline__ void lds_st16(u16* base, int byteoff, bf16 v) {
    *reinterpret_cast<bf16*>(reinterpret_cast<char*>(base) + byteoff) = v;
}

// Convert weights fp32 -> bf16, TRANSPOSED so MFMA B-fragments read contiguous K.
// ws layout: Wqkv_t[384][128] then Wproj_t[128][128]
__global__ void prep_weights_kernel(const float* __restrict__ wqkv,
                                    const float* __restrict__ wproj,
                                    bf16* __restrict__ ws) {
    int i = blockIdx.x * 256 + threadIdx.x;
    if (i < 384 * 128) {
        int n = i >> 7, k = i & 127;
        ws[i] = (bf16)wqkv[k * 384 + n];
    }
    if (i < 128 * 128) {
        int n = i >> 7, k = i & 127;
        ws[384 * 128 + i] = (bf16)wproj[k * 128 + n];
    }
}

// 8 waves / block. Wave w: pair p = w>>1 (old wave p's work), half hf = w&1
// owns token row-tiles mt in {2hf, 2hf+1} (rows [hf*32, hf*32+32)).
// LDS layout identical to round 2 (53,248 B -> 3 blocks/CU = 24 waves/CU):
//   [0, 8192)      Xs : x tile [64][128] bf16 swz; ALIAS Vt[h]=Xs+h*2048 ([32][64] swz);
//                  ALIAS O tile (after PV)
//   [8192, 26624)  QK : Qs[h]=QK+h*2304 [64][36]; Ks[h]=QK+9216+h*2304 [64][36]
//                  ALIAS Pb[pair]=QK+p*4096 [64][64] swz (both waves of pair, disjoint rows)
__launch_bounds__(512, 6)
__global__ void fused_window_attn(const float* __restrict__ x,
                                  const bf16* __restrict__ wqkv_t,
                                  const bf16* __restrict__ wproj_t,
                                  const float* __restrict__ bias,
                                  float* __restrict__ out) {
    __shared__ __align__(16) u16 smem[26624];
    u16* Xs = smem;
    u16* QK = smem + 8192;

    const int tid  = threadIdx.x;
    const int blk  = blockIdx.x;
    const int wv   = tid >> 6;
    const int p    = wv >> 1;     // pair index = head index
    const int hf   = wv & 1;      // token-half: rows [hf*32, hf*32+32)
    const int lane = tid & 63;
    const int lr   = lane & 15;   // A row / B col / D col within 16x16 tile
    const int lg   = lane >> 4;   // k-group for A/B; row-group for D

    // ---------- phase 0: stage x -> Xs (bf16, swizzled); zero pad rows 49..63 ----------
    const float* xw = x + (size_t)blk * (NTOK * CH);
    #pragma unroll
    for (int it = 0; it < 4; ++it) {
        int i = tid + it * 512;
        if (i < (NTOK * CH) / 4) {
            float4 v = reinterpret_cast<const float4*>(xw)[i];
            int e = i * 4, row = e >> 7, col = e & 127;
            bf16x4 pk = { (bf16)v.x, (bf16)v.y, (bf16)v.z, (bf16)v.w };
            *reinterpret_cast<bf16x4*>(reinterpret_cast<char*>(Xs)
                + row * 256 + ((col * 2) ^ ((row & 7) << 4))) = pk;
        }
    }
    if (tid < 240) {  // rows 49..63 = exact zeros -> pad propagates as 0 everywhere
        uint4 zz = {0, 0, 0, 0};
        *reinterpret_cast<uint4*>(reinterpret_cast<char*>(Xs) + 49 * 256 + tid * 16) = zz;
    }
    __syncthreads();

    // ---------- phase 1a: consume own-half of Xs into A-fragments ----------
    bf16x8 af[2][4];  // [m-half-tile][kstep]
    #pragma unroll
    for (int m = 0; m < 2; ++m)
        #pragma unroll
        for (int ks = 0; ks < 4; ++ks) {
            int row = (hf * 2 + m) * 16 + lr;
            af[m][ks] = lds_v8(Xs, row * 256 + ((ks * 64 + lg * 16) ^ ((row & 7) << 4)));
        }
    __syncthreads();  // Xs dead; V writes may now clobber it

    // ---------- phase 1b: QKV GEMM, pair p owns 6 n-tiles, wave does its mt-half ----------
    #pragma unroll
    for (int i = 0; i < 6; ++i) {
        int ntg = p * 6 + i;
        int c   = ntg * 16 + lr;           // output channel of this lane
        bf16x8 bw[4];
        const bf16* wrow = wqkv_t + c * 128 + lg * 8;
        #pragma unroll
        for (int ks = 0; ks < 4; ++ks)
            bw[ks] = *reinterpret_cast<const bf16x8*>(wrow + ks * 32);
        #pragma unroll
        for (int m = 0; m < 2; ++m) {
            f32x4 a = {0.f, 0.f, 0.f, 0.f};
            #pragma unroll
            for (int ks = 0; ks < 4; ++ks) a = MFMA16(af[m][ks], bw[ks], a);
            int mt = hf * 2 + m;
            #pragma unroll
            for (int rg = 0; rg < 4; ++rg) {
                int r = mt * 16 + lg * 4 + rg;   // token row (pad rows are 0 -> safe)
                bf16 vb = (bf16)a[rg];
                if (c < 128) {
                    QK[(c >> 5) * 2304 + r * 36 + (c & 31)] = __builtin_bit_cast(u16, vb);
                } else if (c < 256) {
                    int cc = c - 128;
                    QK[9216 + (cc >> 5) * 2304 + r * 36 + (cc & 31)] = __builtin_bit_cast(u16, vb);
                } else {
                    int cc = c - 256, dh = cc & 31;
                    lds_st16(Xs + (cc >> 5) * 2048,
                             dh * 128 + ((r * 2) ^ ((dh & 7) << 4)), vb);
                }
            }
        }
    }
    __syncthreads();

    // ---------- phase 2: attention, head h = p; wave handles its 2 q-row tiles ----------
    const int h = p;
    const u16* Qh = QK + h * 2304;
    const u16* Kh = QK + 9216 + h * 2304;
    bf16x8 qf[2], kf[4];
    #pragma unroll
    for (int m = 0; m < 2; ++m)
        qf[m] = lds_v8_u8(Qh, ((hf * 2 + m) * 16 + lr) * 72 + lg * 16);
    #pragma unroll
    for (int t = 0; t < 4; ++t)
        kf[t] = lds_v8_u8(Kh, (t * 16 + lr) * 72 + lg * 16);
    __syncthreads();  // Q/K dead; Pb writes may now clobber the QK region

    f32x4 s[2][4];
    #pragma unroll
    for (int m = 0; m < 2; ++m)
        #pragma unroll
        for (int nt = 0; nt < 4; ++nt) {
            f32x4 z = {0.f, 0.f, 0.f, 0.f};
            s[m][nt] = MFMA16(qf[m], kf[nt], z);  // S = q @ k^T (K=32, one step)
        }
    // mask seq columns >= 49 (nt==3, lr>=1) -> P cols 49..63 become exact 0
    if (lr >= 1) {
        #pragma unroll
        for (int m = 0; m < 2; ++m)
            #pragma unroll
            for (int rg = 0; rg < 4; ++rg) s[m][3][rg] = -1e30f;
    }
    // wave-parallel softmax: reduce cols via shfl_xor within 16-lane groups
    float rs[2][4];
    #pragma unroll
    for (int m = 0; m < 2; ++m) {
        #pragma unroll
        for (int rg = 0; rg < 4; ++rg) {
            float mx = fmaxf(fmaxf(s[m][0][rg], s[m][1][rg]),
                             fmaxf(s[m][2][rg], s[m][3][rg]));
            #pragma unroll
            for (int d = 1; d < 16; d <<= 1) mx = fmaxf(mx, __shfl_xor(mx, d));
            float l = 0.f;
            #pragma unroll
            for (int nt = 0; nt < 4; ++nt) {
                float e = exp2f((s[m][nt][rg] - mx) * CEXP);
                s[m][nt][rg] = e;
                l += e;
            }
            #pragma unroll
            for (int d = 1; d < 16; d <<= 1) l += __shfl_xor(l, d);
            rs[m][rg] = 1.f / l;   // fold normalization into O rescale
        }
    }
    // unnormalized P -> Pb (bf16, swizzled); per-pair slab, waves write disjoint rows
    u16* Pw = QK + p * 4096;
    #pragma unroll
    for (int m = 0; m < 2; ++m) {
        int mt = hf * 2 + m;
        #pragma unroll
        for (int nt = 0; nt < 4; ++nt)
            #pragma unroll
            for (int rg = 0; rg < 4; ++rg) {
                int row = mt * 16 + lg * 4 + rg;
                int col = nt * 16 + lr;
                lds_st16(Pw, row * 128 + ((col * 2) ^ ((row & 7) << 4)),
                         (bf16)s[m][nt][rg]);
            }
    }
    // O = P @ V  (K = 64 padded seq; V pad cols are exact 0).
    // P rows read here were written by this same wave -> wave-local RAW, no barrier.
    const u16* Vh = Xs + h * 2048;
    f32x4 o[2][2];
    #pragma unroll
    for (int m = 0; m < 2; ++m) {
        f32x4 z = {0.f, 0.f, 0.f, 0.f};
        o[m][0] = z; o[m][1] = z;
    }
    #pragma unroll
    for (int ks = 0; ks < 2; ++ks) {
        bf16x8 vf2[2];
        #pragma unroll
        for (int ot = 0; ot < 2; ++ot) {
            int vr = ot * 16 + lr;  // dh row of Vt
            vf2[ot] = lds_v8(Vh, vr * 128 + ((ks * 64 + lg * 16) ^ ((vr & 7) << 4)));
        }
        #pragma unroll
        for (int m = 0; m < 2; ++m) {
            int pr = (hf * 2 + m) * 16 + lr;
            bf16x8 pf = lds_v8(Pw, pr * 128 + ((ks * 64 + lg * 16) ^ ((pr & 7) << 4)));
            #pragma unroll
            for (int ot = 0; ot < 2; ++ot) o[m][ot] = MFMA16(pf, vf2[ot], o[m][ot]);
        }
    }
    __syncthreads();  // all PV reads of Vt done; O writes may now clobber Xs

    // rescale by 1/rowsum, write O tile into Xs
    #pragma unroll
    for (int m = 0; m < 2; ++m) {
        int mt = hf * 2 + m;
        #pragma unroll
        for (int ot = 0; ot < 2; ++ot)
            #pragma unroll
            for (int rg = 0; rg < 4; ++rg) {
                int r = mt * 16 + lg * 4 + rg;
                int c = h * 32 + ot * 16 + lr;
                lds_st16(Xs, r * 256 + ((c * 2) ^ ((r & 7) << 4)),
                         (bf16)(o[m][ot][rg] * rs[m][rg]));
            }
    }
    __syncthreads();

    // ---------- phase 3: proj GEMM (49x128 @ 128x128) + bias ----------
    // pair p owns output ch tiles {2p, 2p+1}; wave does its mt-half
    bf16x8 ofr[2][4];
    #pragma unroll
    for (int m = 0; m < 2; ++m)
        #pragma unroll
        for (int ks = 0; ks < 4; ++ks) {
            int row = (hf * 2 + m) * 16 + lr;
            ofr[m][ks] = lds_v8(Xs, row * 256 + ((ks * 64 + lg * 16) ^ ((row & 7) << 4)));
        }
    #pragma unroll
    for (int i = 0; i < 2; ++i) {
        int ntg = p * 2 + i;
        int c   = ntg * 16 + lr;
        bf16x8 bw[4];
        const bf16* wrow = wproj_t + c * 128 + lg * 8;
        #pragma unroll
        for (int ks = 0; ks < 4; ++ks)
            bw[ks] = *reinterpret_cast<const bf16x8*>(wrow + ks * 32);
        float bv = bias[c];
        #pragma unroll
        for (int m = 0; m < 2; ++m) {
            f32x4 a = {0.f, 0.f, 0.f, 0.f};
            #pragma unroll
            for (int ks = 0; ks < 4; ++ks) a = MFMA16(ofr[m][ks], bw[ks], a);
            int mt = hf * 2 + m;
            #pragma unroll
            for (int rg = 0; rg < 4; ++rg) {
                int r = mt * 16 + lg * 4 + rg;
                if (r < NTOK)
                    out[((size_t)blk * NTOK + r) * CH + c] = a[rg] + bv;
            }
        }
    }
}

extern "C" void kernel_launch(void* const* d_in, const int* in_sizes, int n_in,
                              void* d_out, int out_size, void* d_ws, size_t ws_size,
                              hipStream_t stream) {
    const float* x     = (const float*)d_in[0];
    const float* wqkv  = (const float*)d_in[1];
    const float* wproj = (const float*)d_in[2];
    const float* bias  = (const float*)d_in[3];
    float* out = (float*)d_out;
    bf16* ws   = (bf16*)d_ws;

    constexpr size_t WS_NEED = (size_t)(384 * 128 + 128 * 128) * sizeof(u16);
    if (ws_size < WS_NEED) return;  // scratch too small: fail visibly (zero output)

    prep_weights_kernel<<<192, 256, 0, stream>>>(wqkv, wproj, ws);
    fused_window_attn<<<4096, 512, 0, stream>>>(x, ws, ws + 384 * 128, bias, out);
}

// Round 4
// 98.498 us; speedup vs baseline: 1.5861x; 1.5861x over previous
//
#include <hip/hip_runtime.h>
#include <hip/hip_bf16.h>

typedef unsigned short u16;
typedef __bf16 bf16;
typedef __attribute__((ext_vector_type(8))) __bf16 bf16x8;
typedef __attribute__((ext_vector_type(4))) __bf16 bf16x4;
typedef __attribute__((ext_vector_type(4))) float f32x4;

#define MFMA16(A,B,C) __builtin_amdgcn_mfma_f32_16x16x32_bf16(A,B,C,0,0,0)

constexpr int NTOK = 49;
constexpr int CH   = 128;
// softmax scale folded into exp2: SCALE * log2(e)
constexpr float CEXP = 0.17677669529663687f * 1.4426950408889634f;

__device__ __forceinline__ bf16x8 lds_v8(const u16* base, int byteoff) {
    return *reinterpret_cast<const bf16x8*>(reinterpret_cast<const char*>(base) + byteoff);
}
// 16B fragment from 8B-aligned addr (stride-72 rows): two b64 reads
__device__ __forceinline__ bf16x8 lds_v8_u8(const u16* base, int byteoff) {
    bf16x4 lo = *reinterpret_cast<const bf16x4*>(reinterpret_cast<const char*>(base) + byteoff);
    bf16x4 hi = *reinterpret_cast<const bf16x4*>(reinterpret_cast<const char*>(base) + byteoff + 8);
    bf16x8 r;
    r[0]=lo[0]; r[1]=lo[1]; r[2]=lo[2]; r[3]=lo[3];
    r[4]=hi[0]; r[5]=hi[1]; r[6]=hi[2]; r[7]=hi[3];
    return r;
}
// packed 4x bf16 (8B) store
__device__ __forceinline__ void lds_st64(u16* base, int byteoff,
                                         float a0, float a1, float a2, float a3) {
    bf16x4 v = {(bf16)a0, (bf16)a1, (bf16)a2, (bf16)a3};
    *reinterpret_cast<bf16x4*>(reinterpret_cast<char*>(base) + byteoff) = v;
}

// Weights fp32 -> bf16, transposed: ws = Wqkv_t[384][128] then Wproj_t[128][128]
__global__ void prep_weights_kernel(const float* __restrict__ wqkv,
                                    const float* __restrict__ wproj,
                                    bf16* __restrict__ ws) {
    int i = blockIdx.x * 256 + threadIdx.x;
    if (i < 384 * 128) {
        int n = i >> 7, k = i & 127;
        ws[i] = (bf16)wqkv[k * 384 + n];
    }
    if (i < 128 * 128) {
        int n = i >> 7, k = i & 127;
        ws[384 * 128 + i] = (bf16)wproj[k * 128 + n];
    }
}

// 4 waves/block, wave wv owns head wv end-to-end. LDS 53,248 B -> 3 blocks/CU:
//   [0, 8192)      Xs: X tile [64 tok][128 ch] bf16, 256B rows, byte^=((tok&7)<<4)
//                  ALIAS Vh = Xs + wv*2048: V^T [32 dh][64 seq], 128B rows, swz((dh&7)<<4)
//                      (written post-B2, read only by owning wave)
//                  ALIAS O tile [64 tok][128 ch] (written post-B3)
//   [8192, 26624)  per-head slab h at + h*4608 u16 (9216B):
//                      Qh [64 tok][36 u16] (72B rows), Kh = Qh + 2304
//                  ALIAS Pw = own slab: P [64 q][64 s], 128B rows, swz((q&7)<<4)
//                      (8KB < 9216B, strictly wave-local -> no barrier)
__launch_bounds__(256, 3)
__global__ void fused_window_attn(const float* __restrict__ x,
                                  const bf16* __restrict__ wqkv_t,
                                  const bf16* __restrict__ wproj_t,
                                  const float* __restrict__ bias,
                                  float* __restrict__ out) {
    __shared__ __align__(16) u16 smem[26624];
    u16* Xs = smem;
    u16* QK = smem + 8192;

    const int tid  = threadIdx.x;
    const int blk  = blockIdx.x;
    const int wv   = tid >> 6;    // wave == head
    const int lane = tid & 63;
    const int lr   = lane & 15;
    const int lg   = lane >> 4;

    u16* Qh = QK + wv * 4608;
    u16* Kh = Qh + 2304;
    u16* Pw = Qh;                 // alias: P over own Q+K (wave-local, post-frag-load)
    u16* Vh = Xs + wv * 2048;

    // ---------- phase 0: stage x -> Xs (bf16, swizzled); zero pad rows ----------
    const float* xw = x + (size_t)blk * (NTOK * CH);
    #pragma unroll
    for (int it = 0; it < 7; ++it) {
        int i = tid + it * 256;
        if (i < (NTOK * CH) / 4) {
            float4 v = reinterpret_cast<const float4*>(xw)[i];
            int e = i * 4, row = e >> 7, col = e & 127;
            bf16x4 pk = { (bf16)v.x, (bf16)v.y, (bf16)v.z, (bf16)v.w };
            *reinterpret_cast<bf16x4*>(reinterpret_cast<char*>(Xs)
                + row * 256 + ((col * 2) ^ ((row & 7) << 4))) = pk;
        }
    }
    if (tid < 240) {  // rows 49..63 = exact zeros
        uint4 zz = {0, 0, 0, 0};
        *reinterpret_cast<uint4*>(reinterpret_cast<char*>(Xs) + 49 * 256 + tid * 16) = zz;
    }
    __syncthreads();  // B1

    // X fragments: used as B (Q/K gemms) and as A (V gemm) — same bytes
    bf16x8 xf[4][4];  // [tok-tile][kstep]
    #pragma unroll
    for (int tt = 0; tt < 4; ++tt)
        #pragma unroll
        for (int ks = 0; ks < 4; ++ks) {
            int row = tt * 16 + lr;
            xf[tt][ks] = lds_v8(Xs, row * 256 + ((ks * 64 + lg * 16) ^ ((row & 7) << 4)));
        }
    __syncthreads();  // B2: Xs (as X) dead; V stores may clobber it

    // ---------- phase 1: QKV GEMM, head-owned, all stores packed b64 ----------
    // Q,K: mfma(A=W, B=X^T) -> D: lane col = tok, regs = 4 consecutive channels
    #pragma unroll
    for (int mt = 0; mt < 4; ++mt) {
        int ct = (mt < 2) ? (2 * wv + mt) : (8 + 2 * wv + (mt - 2));
        bf16x8 wf[4];
        const bf16* wrow = wqkv_t + (ct * 16 + lr) * 128 + lg * 8;
        #pragma unroll
        for (int ks = 0; ks < 4; ++ks)
            wf[ks] = *reinterpret_cast<const bf16x8*>(wrow + ks * 32);
        u16* dst = (mt < 2) ? Qh : Kh;
        int dh0 = (mt & 1) * 16 + lg * 4;
        #pragma unroll
        for (int tt = 0; tt < 4; ++tt) {
            f32x4 a = {0.f, 0.f, 0.f, 0.f};
            #pragma unroll
            for (int ks = 0; ks < 4; ++ks) a = MFMA16(wf[ks], xf[tt][ks], a);
            int tok = tt * 16 + lr;
            lds_st64(dst, tok * 72 + dh0 * 2, a[0], a[1], a[2], a[3]);
        }
    }
    // V: mfma(A=X, B=W) -> D: lane col = dh, regs = 4 consecutive toks -> Vt[dh][seq]
    #pragma unroll
    for (int i = 0; i < 2; ++i) {
        int ct = 16 + 2 * wv + i;
        bf16x8 wf[4];
        const bf16* wrow = wqkv_t + (ct * 16 + lr) * 128 + lg * 8;
        #pragma unroll
        for (int ks = 0; ks < 4; ++ks)
            wf[ks] = *reinterpret_cast<const bf16x8*>(wrow + ks * 32);
        int dh = i * 16 + lr;
        #pragma unroll
        for (int tt = 0; tt < 4; ++tt) {
            f32x4 a = {0.f, 0.f, 0.f, 0.f};
            #pragma unroll
            for (int ks = 0; ks < 4; ++ks) a = MFMA16(xf[tt][ks], wf[ks], a);
            lds_st64(Vh, dh * 128 + ((tt * 32 + lg * 8) ^ ((dh & 7) << 4)),
                     a[0], a[1], a[2], a[3]);
        }
    }

    // ---------- phase 2: attention (all wave-local LDS) ----------
    bf16x8 qf[4], kf[4];
    #pragma unroll
    for (int t = 0; t < 4; ++t) {
        qf[t] = lds_v8_u8(Qh, (t * 16 + lr) * 72 + lg * 16);
        kf[t] = lds_v8_u8(Kh, (t * 16 + lr) * 72 + lg * 16);
    }
    // S^T tiles: mfma(K, Q): lane col = q, regs = s rows (st*16 + lg*4 + rg)
    f32x4 s[4][4];  // [qt][st]
    #pragma unroll
    for (int qt = 0; qt < 4; ++qt)
        #pragma unroll
        for (int st = 0; st < 4; ++st) {
            f32x4 z = {0.f, 0.f, 0.f, 0.f};
            s[qt][st] = MFMA16(kf[st], qf[qt], z);
        }
    // V fragments (own slab), then barrier so O may clobber Xs later
    bf16x8 vf[2][2];
    #pragma unroll
    for (int dht = 0; dht < 2; ++dht)
        #pragma unroll
        for (int ks = 0; ks < 2; ++ks) {
            int dh = dht * 16 + lr;
            vf[dht][ks] = lds_v8(Vh, dh * 128 + ((ks * 64 + lg * 16) ^ ((dh & 7) << 4)));
        }
    __syncthreads();  // B3: all Vt reads secured in regs

    // mask s >= 49 (st==3: s = 48 + lg*4 + rg)
    #pragma unroll
    for (int qt = 0; qt < 4; ++qt) {
        if (lg > 0) s[qt][3][0] = -1e30f;
        s[qt][3][1] = -1e30f; s[qt][3][2] = -1e30f; s[qt][3][3] = -1e30f;
    }
    // softmax: in-lane reduce over 16 s-values + 2 shfl_xor (lanes lr+16*lg)
    float rs[4];
    #pragma unroll
    for (int qt = 0; qt < 4; ++qt) {
        float mx = -1e30f;
        #pragma unroll
        for (int st = 0; st < 4; ++st)
            #pragma unroll
            for (int rg = 0; rg < 4; ++rg) mx = fmaxf(mx, s[qt][st][rg]);
        mx = fmaxf(mx, __shfl_xor(mx, 16));
        mx = fmaxf(mx, __shfl_xor(mx, 32));
        float l = 0.f;
        #pragma unroll
        for (int st = 0; st < 4; ++st)
            #pragma unroll
            for (int rg = 0; rg < 4; ++rg) {
                float e = exp2f((s[qt][st][rg] - mx) * CEXP);
                s[qt][st][rg] = e;
                l += e;
            }
        l += __shfl_xor(l, 16);
        l += __shfl_xor(l, 32);
        rs[qt] = 1.f / l;
    }
    // P -> LDS, packed b64 (4 consecutive s per reg-group), wave-local slab
    #pragma unroll
    for (int qt = 0; qt < 4; ++qt) {
        int q = qt * 16 + lr;
        #pragma unroll
        for (int st = 0; st < 4; ++st)
            lds_st64(Pw, q * 128 + ((st * 32 + lg * 8) ^ ((q & 7) << 4)),
                     s[qt][st][0], s[qt][st][1], s[qt][st][2], s[qt][st][3]);
    }
    // O^T = V^T @ P^T: mfma(A=Vt, B=P^T): lane col = q, regs = 4 consecutive dh
    f32x4 o[2][4];
    #pragma unroll
    for (int dht = 0; dht < 2; ++dht)
        #pragma unroll
        for (int qt = 0; qt < 4; ++qt) { f32x4 z = {0.f,0.f,0.f,0.f}; o[dht][qt] = z; }
    #pragma unroll
    for (int ks = 0; ks < 2; ++ks)
        #pragma unroll
        for (int qt = 0; qt < 4; ++qt) {
            int q = qt * 16 + lr;
            bf16x8 pf = lds_v8(Pw, q * 128 + ((ks * 64 + lg * 16) ^ ((q & 7) << 4)));
            #pragma unroll
            for (int dht = 0; dht < 2; ++dht)
                o[dht][qt] = MFMA16(vf[dht][ks], pf, o[dht][qt]);
        }
    // O -> Xs [tok][ch], packed b64 (4 consecutive ch in regs), rescaled by 1/l
    #pragma unroll
    for (int dht = 0; dht < 2; ++dht)
        #pragma unroll
        for (int qt = 0; qt < 4; ++qt) {
            int q = qt * 16 + lr;
            float scl = rs[qt];
            lds_st64(Xs, q * 256 + ((wv * 64 + dht * 32 + lg * 8) ^ ((q & 7) << 4)),
                     o[dht][qt][0] * scl, o[dht][qt][1] * scl,
                     o[dht][qt][2] * scl, o[dht][qt][3] * scl);
        }
    __syncthreads();  // B4

    // ---------- phase 3: proj GEMM, D has 4 consecutive channels -> float4 out ----------
    bf16x8 of[4][4];
    #pragma unroll
    for (int tt = 0; tt < 4; ++tt)
        #pragma unroll
        for (int ks = 0; ks < 4; ++ks) {
            int row = tt * 16 + lr;
            of[tt][ks] = lds_v8(Xs, row * 256 + ((ks * 64 + lg * 16) ^ ((row & 7) << 4)));
        }
    #pragma unroll
    for (int i = 0; i < 2; ++i) {
        int ct = 2 * wv + i;
        bf16x8 wf[4];
        const bf16* wrow = wproj_t + (ct * 16 + lr) * 128 + lg * 8;
        #pragma unroll
        for (int ks = 0; ks < 4; ++ks)
            wf[ks] = *reinterpret_cast<const bf16x8*>(wrow + ks * 32);
        float4 bv = *reinterpret_cast<const float4*>(bias + ct * 16 + lg * 4);
        #pragma unroll
        for (int tt = 0; tt < 4; ++tt) {
            f32x4 a = {0.f, 0.f, 0.f, 0.f};
            #pragma unroll
            for (int ks = 0; ks < 4; ++ks) a = MFMA16(wf[ks], of[tt][ks], a);
            int tok = tt * 16 + lr;
            if (tok < NTOK) {
                float4 r = { a[0] + bv.x, a[1] + bv.y, a[2] + bv.z, a[3] + bv.w };
                *reinterpret_cast<float4*>(
                    out + ((size_t)blk * NTOK + tok) * CH + ct * 16 + lg * 4) = r;
            }
        }
    }
}

extern "C" void kernel_launch(void* const* d_in, const int* in_sizes, int n_in,
                              void* d_out, int out_size, void* d_ws, size_t ws_size,
                              hipStream_t stream) {
    const float* x     = (const float*)d_in[0];
    const float* wqkv  = (const float*)d_in[1];
    const float* wproj = (const float*)d_in[2];
    const float* bias  = (const float*)d_in[3];
    float* out = (float*)d_out;
    bf16* ws   = (bf16*)d_ws;

    constexpr size_t WS_NEED = (size_t)(384 * 128 + 128 * 128) * sizeof(u16);
    if (ws_size < WS_NEED) return;

    prep_weights_kernel<<<192, 256, 0, stream>>>(wqkv, wproj, ws);
    fused_window_attn<<<4096, 256, 0, stream>>>(x, ws, ws + 384 * 128, bias, out);
}